// Round 1
// baseline (335.971 us; speedup 1.0000x reference)
//
#include <hip/hip_runtime.h>
#include <math.h>

#define BSZ 2
#define CDIM 256
#define LSEQ 4096
#define DIN 512
#define NST 16
#define NC 128       // chunks per batch
#define CT 32        // chunk length (NC*CT = LSEQ)
#define LOG2E 1.44269504088896f

// ---------------- LayerNorm (tiled transpose) ----------------
// x: (B, C, L) -> xs: (B, L, C) layernormed over C
__global__ __launch_bounds__(256) void k_ln(const float* __restrict__ x,
                                            const float* __restrict__ g,
                                            const float* __restrict__ beta,
                                            float* __restrict__ xs) {
    int b  = blockIdx.x >> 7;          // 128 tiles of 32 tokens per batch
    int l0 = (blockIdx.x & 127) * 32;
    int tid = threadIdx.x;
    __shared__ float T[256][33];
    __shared__ float ps[8][32], ps2[8][32];
    __shared__ float mus[32], rs[32];

    #pragma unroll
    for (int i = 0; i < 8; ++i) {
        int f = i * 256 + tid;          // 2048 float4 loads
        int c = f >> 3, lq = f & 7;
        float4 v = *(const float4*)(x + (b * 256 + c) * 4096 + l0 + lq * 4);
        T[c][lq * 4 + 0] = v.x; T[c][lq * 4 + 1] = v.y;
        T[c][lq * 4 + 2] = v.z; T[c][lq * 4 + 3] = v.w;
    }
    __syncthreads();
    {
        int lt = tid & 31, q = tid >> 5;
        float s = 0.f, s2 = 0.f;
        #pragma unroll
        for (int c = q * 32; c < q * 32 + 32; ++c) {
            float v = T[c][lt];
            s += v; s2 += v * v;
        }
        ps[q][lt] = s; ps2[q][lt] = s2;
    }
    __syncthreads();
    if (tid < 32) {
        float ts = 0.f, ts2 = 0.f;
        #pragma unroll
        for (int q = 0; q < 8; ++q) { ts += ps[q][tid]; ts2 += ps2[q][tid]; }
        float mu  = ts * (1.f / 256.f);
        float var = ts2 * (1.f / 256.f) - mu * mu;
        mus[tid] = mu;
        rs[tid]  = rsqrtf(var + 1e-5f);
    }
    __syncthreads();
    float gg = g[tid], bb = beta[tid];
    #pragma unroll
    for (int i = 0; i < 32; ++i) {
        float v = (T[tid][i] - mus[i]) * rs[i] * gg + bb;
        xs[(b * 4096 + l0 + i) * 256 + tid] = v;
    }
}

// ---------------- GEMM1: xz = xs @ W_in, split into xin / z ----------------
// A: (8192, 256), W: (256, 1024). BM=BN=128, BK=16, 8x8 micro-tile.
__global__ __launch_bounds__(256) void k_gemm1(const float* __restrict__ A,
                                               const float* __restrict__ W,
                                               float* __restrict__ xin,
                                               float* __restrict__ zout) {
    __shared__ float As[16][128];
    __shared__ float Bs[16][128];
    int tid = threadIdx.x;
    int m0 = blockIdx.x * 128;
    int n0 = blockIdx.y * 128;
    int tm = tid >> 4, tn = tid & 15;
    float acc[8][8] = {};
    for (int k0 = 0; k0 < 256; k0 += 16) {
        #pragma unroll
        for (int i = 0; i < 2; ++i) {
            int f = tid * 2 + i;
            int r = f >> 2, kq = f & 3;
            float4 v = *(const float4*)(A + (m0 + r) * 256 + k0 + kq * 4);
            As[kq * 4 + 0][r] = v.x; As[kq * 4 + 1][r] = v.y;
            As[kq * 4 + 2][r] = v.z; As[kq * 4 + 3][r] = v.w;
        }
        #pragma unroll
        for (int i = 0; i < 2; ++i) {
            int f = tid * 2 + i;
            int kk = f >> 5, cq = f & 31;
            *(float4*)&Bs[kk][cq * 4] = *(const float4*)(W + (k0 + kk) * 1024 + n0 + cq * 4);
        }
        __syncthreads();
        #pragma unroll
        for (int kk = 0; kk < 16; ++kk) {
            float a[8], bb[8];
            *(float4*)(a)     = *(float4*)&As[kk][tm * 8];
            *(float4*)(a + 4) = *(float4*)&As[kk][tm * 8 + 4];
            *(float4*)(bb)     = *(float4*)&Bs[kk][tn * 8];
            *(float4*)(bb + 4) = *(float4*)&Bs[kk][tn * 8 + 4];
            #pragma unroll
            for (int i = 0; i < 8; ++i)
                #pragma unroll
                for (int j = 0; j < 8; ++j)
                    acc[i][j] += a[i] * bb[j];
        }
        __syncthreads();
    }
    bool isz = (n0 >= 512);
    float* out = isz ? zout : xin;
    int nb = isz ? n0 - 512 : n0;
    #pragma unroll
    for (int i = 0; i < 8; ++i) {
        int row = m0 + tm * 8 + i;
        #pragma unroll
        for (int j = 0; j < 8; j += 4) {
            float4 v = make_float4(acc[i][j], acc[i][j + 1], acc[i][j + 2], acc[i][j + 3]);
            *(float4*)&out[row * 512 + nb + tn * 8 + j] = v;
        }
    }
}

// ---------------- depthwise causal conv(4) + SiLU ----------------
__global__ __launch_bounds__(256) void k_conv(const float* __restrict__ xin,
                                              const float* __restrict__ cw,
                                              const float* __restrict__ cb,
                                              float* __restrict__ xc) {
    int idx = blockIdx.x * 256 + threadIdx.x;   // B*L*D
    int d = idx & 511;
    int r = idx >> 9;
    int l = r & 4095;
    int b = r >> 12;
    float s = cb[d];
    #pragma unroll
    for (int k = 0; k < 4; ++k) {
        int ll = l - 3 + k;
        if (ll >= 0) s += cw[d * 4 + k] * xin[(((b << 12) + ll) << 9) + d];
    }
    float sig = 1.f / (1.f + expf(-s));
    xc[idx] = s * sig;
}

// ---------------- x-proj (K=512,N=48) + dt-proj (K=16,N=512) + softplus ----
__global__ __launch_bounds__(256) void k_xproj(const float* __restrict__ xc,
                                               const float* __restrict__ Wx,
                                               const float* __restrict__ Wdt,
                                               const float* __restrict__ bdt,
                                               float* __restrict__ dtp,
                                               float* __restrict__ Bm,
                                               float* __restrict__ Cm) {
    int l = blockIdx.x & 4095, b = blockIdx.x >> 12;
    int tid = threadIdx.x;
    __shared__ float xls[512];
    __shared__ float part[4][48];
    __shared__ float dbl_s[48];
    int base = ((b << 12) + l) * 512;
    xls[tid]       = xc[base + tid];
    xls[tid + 256] = xc[base + 256 + tid];
    __syncthreads();
    if (tid < 192) {
        int j = tid % 48, seg = tid / 48;
        int k0 = seg * 128;
        float s = 0.f;
        for (int k = 0; k < 128; ++k) s += xls[k0 + k] * Wx[(k0 + k) * 48 + j];
        part[seg][j] = s;
    }
    __syncthreads();
    if (tid < 48) {
        float v = part[0][tid] + part[1][tid] + part[2][tid] + part[3][tid];
        dbl_s[tid] = v;
        int tok = (b << 12) + l;
        if (tid >= 32)      Cm[tok * 16 + tid - 32] = v;
        else if (tid >= 16) Bm[tok * 16 + tid - 16] = v;
    }
    __syncthreads();
    #pragma unroll
    for (int half = 0; half < 2; ++half) {
        int dd = half * 256 + tid;
        float s = bdt[dd];
        #pragma unroll
        for (int rr = 0; rr < 16; ++rr) s += dbl_s[rr] * Wdt[rr * 512 + dd];
        dtp[base + dd] = (s > 20.f) ? s : log1pf(expf(s));
    }
}

// ---------------- scan phase A: chunk-local state (h from 0) + sum_dt -------
__global__ __launch_bounds__(512) void k_scanA(const float* __restrict__ dtp,
                                               const float* __restrict__ xc,
                                               const float* __restrict__ Bm,
                                               const float* __restrict__ A_log,
                                               float* __restrict__ S,
                                               float* __restrict__ sdt) {
    int b = blockIdx.x >> 7;
    int ch = blockIdx.x & 127;
    int d = threadIdx.x;
    __shared__ float Bb[CT][16];
    {
        int t = threadIdx.x >> 4, n = threadIdx.x & 15;
        Bb[t][n] = Bm[((b << 12) + ch * CT + t) * 16 + n];
    }
    __syncthreads();
    float a2[16];
    #pragma unroll
    for (int n = 0; n < 16; ++n) a2[n] = -expf(A_log[d * 16 + n]) * LOG2E;
    float h[16] = {};
    float sum_dt = 0.f;
    int base = ((b << 12) + ch * CT) * 512 + d;
    for (int t = 0; t < CT; ++t) {
        float dv = dtp[base + t * 512];
        float xv = xc[base + t * 512];
        sum_dt += dv;
        float dx = dv * xv;
        #pragma unroll
        for (int n = 0; n < 16; ++n) {
            float w = exp2f(dv * a2[n]);
            h[n] = w * h[n] + dx * Bb[t][n];
        }
    }
    int so = ((b * NC + ch) * 512 + d) * 16;
    #pragma unroll
    for (int n = 0; n < 16; n += 4)
        *(float4*)&S[so + n] = make_float4(h[n], h[n + 1], h[n + 2], h[n + 3]);
    sdt[(b * NC + ch) * 512 + d] = sum_dt;
}

// ---------------- scan phase B: combine chunk states sequentially ----------
__global__ __launch_bounds__(256) void k_comb(const float* __restrict__ S,
                                              const float* __restrict__ sdt,
                                              const float* __restrict__ A_log,
                                              float* __restrict__ hinit) {
    int gidx = blockIdx.x * 256 + threadIdx.x;  // 16384 = B*D*N
    int n = gidx & 15;
    int d = (gidx >> 4) & 511;
    int b = gidx >> 13;
    float a2 = -expf(A_log[d * 16 + n]) * LOG2E;
    float h = 0.f;
    for (int c = 0; c < NC; ++c) {
        int ci = (b * NC + c) * 512 + d;
        hinit[ci * 16 + n] = h;
        float w = exp2f(a2 * sdt[ci]);
        h = w * h + S[ci * 16 + n];
    }
}

// ---------------- scan phase C: replay with h_init, fuse skip + SiLU gate ---
__global__ __launch_bounds__(512) void k_scanC(const float* __restrict__ dtp,
                                               const float* __restrict__ xc,
                                               const float* __restrict__ Bm,
                                               const float* __restrict__ Cm,
                                               const float* __restrict__ A_log,
                                               const float* __restrict__ hinit,
                                               const float* __restrict__ Dskip,
                                               const float* __restrict__ zin,
                                               float* __restrict__ yact) {
    int b = blockIdx.x >> 7;
    int ch = blockIdx.x & 127;
    int d = threadIdx.x;
    __shared__ float Bb[CT][16], Cb[CT][16];
    {
        int t = threadIdx.x >> 4, n = threadIdx.x & 15;
        int li = ((b << 12) + ch * CT + t) * 16 + n;
        Bb[t][n] = Bm[li];
        Cb[t][n] = Cm[li];
    }
    __syncthreads();
    float a2[16], h[16];
    #pragma unroll
    for (int n = 0; n < 16; ++n) a2[n] = -expf(A_log[d * 16 + n]) * LOG2E;
    int hi = ((b * NC + ch) * 512 + d) * 16;
    #pragma unroll
    for (int n = 0; n < 16; n += 4) {
        float4 v = *(const float4*)&hinit[hi + n];
        h[n] = v.x; h[n + 1] = v.y; h[n + 2] = v.z; h[n + 3] = v.w;
    }
    float Dsk = Dskip[d];
    int base = ((b << 12) + ch * CT) * 512 + d;
    for (int t = 0; t < CT; ++t) {
        float dv = dtp[base + t * 512];
        float xv = xc[base + t * 512];
        float zv = zin[base + t * 512];
        float dx = dv * xv;
        float y = 0.f;
        #pragma unroll
        for (int n = 0; n < 16; ++n) {
            float w = exp2f(dv * a2[n]);
            h[n] = w * h[n] + dx * Bb[t][n];
            y += h[n] * Cb[t][n];
        }
        y += xv * Dsk;
        float sig = 1.f / (1.f + expf(-zv));
        yact[base + t * 512] = y * zv * sig;
    }
}

// ---------------- GEMM3: out = yact @ W_out, written transposed (B,C,L) ----
// A: (8192, 512), W: (512, 256). BM=128, BN=64, BK=16, 8x4 micro.
__global__ __launch_bounds__(256) void k_gemm3(const float* __restrict__ A,
                                               const float* __restrict__ W,
                                               float* __restrict__ out) {
    __shared__ float As[16][128];
    __shared__ float Bs[16][64];
    __shared__ float T[64][129];
    int tid = threadIdx.x;
    int m0 = blockIdx.x * 128;
    int n0 = blockIdx.y * 64;
    int tm = tid >> 4, tn = tid & 15;
    float acc[8][4] = {};
    for (int k0 = 0; k0 < 512; k0 += 16) {
        #pragma unroll
        for (int i = 0; i < 2; ++i) {
            int f = tid * 2 + i;
            int r = f >> 2, kq = f & 3;
            float4 v = *(const float4*)(A + (m0 + r) * 512 + k0 + kq * 4);
            As[kq * 4 + 0][r] = v.x; As[kq * 4 + 1][r] = v.y;
            As[kq * 4 + 2][r] = v.z; As[kq * 4 + 3][r] = v.w;
        }
        {
            int kk = tid >> 4, cq = tid & 15;
            *(float4*)&Bs[kk][cq * 4] = *(const float4*)(W + (k0 + kk) * 256 + n0 + cq * 4);
        }
        __syncthreads();
        #pragma unroll
        for (int kk = 0; kk < 16; ++kk) {
            float a[8], bb[4];
            *(float4*)(a)     = *(float4*)&As[kk][tm * 8];
            *(float4*)(a + 4) = *(float4*)&As[kk][tm * 8 + 4];
            *(float4*)(bb)    = *(float4*)&Bs[kk][tn * 4];
            #pragma unroll
            for (int i = 0; i < 8; ++i)
                #pragma unroll
                for (int j = 0; j < 4; ++j)
                    acc[i][j] += a[i] * bb[j];
        }
        __syncthreads();
    }
    #pragma unroll
    for (int i = 0; i < 8; ++i)
        #pragma unroll
        for (int j = 0; j < 4; ++j)
            T[tn * 4 + j][tm * 8 + i] = acc[i][j];
    __syncthreads();
    int b = m0 >> 12;
    int l0 = m0 & 4095;
    #pragma unroll
    for (int i = 0; i < 8; ++i) {
        int f = i * 256 + tid;     // 2048 float4s
        int col = f >> 5, lq = f & 31;
        float4 v = make_float4(T[col][lq * 4], T[col][lq * 4 + 1],
                               T[col][lq * 4 + 2], T[col][lq * 4 + 3]);
        *(float4*)(out + b * (256 * 4096) + (n0 + col) * 4096 + l0 + lq * 4) = v;
    }
}

extern "C" void kernel_launch(void* const* d_in, const int* in_sizes, int n_in,
                              void* d_out, int out_size, void* d_ws, size_t ws_size,
                              hipStream_t stream) {
    const float* x      = (const float*)d_in[0];
    const float* ln_g   = (const float*)d_in[1];
    const float* ln_b   = (const float*)d_in[2];
    const float* W_in   = (const float*)d_in[3];
    const float* conv_w = (const float*)d_in[4];
    const float* conv_b = (const float*)d_in[5];
    const float* W_x    = (const float*)d_in[6];
    const float* W_dt   = (const float*)d_in[7];
    const float* b_dt   = (const float*)d_in[8];
    const float* A_log  = (const float*)d_in[9];
    const float* D_skip = (const float*)d_in[10];
    const float* W_out  = (const float*)d_in[11];
    float* out = (float*)d_out;

    float* ws = (float*)d_ws;
    float* xs    = ws;                   // 2,097,152
    float* xin   = xs    + 2097152;      // 4,194,304
    float* z     = xin   + 4194304;      // 4,194,304
    float* xc    = z     + 4194304;      // 4,194,304
    float* dtp   = xc    + 4194304;      // 4,194,304
    float* Bm    = dtp   + 4194304;      // 131,072
    float* Cm    = Bm    + 131072;       // 131,072
    float* Sst   = Cm    + 131072;       // 2,097,152
    float* sdt   = Sst   + 2097152;      // 131,072
    float* hinit = sdt   + 131072;       // 2,097,152
    float* yact  = xin;                  // reuse: xin dead after conv

    k_ln<<<dim3(256), dim3(256), 0, stream>>>(x, ln_g, ln_b, xs);
    k_gemm1<<<dim3(64, 8), dim3(256), 0, stream>>>(xs, W_in, xin, z);
    k_conv<<<dim3(16384), dim3(256), 0, stream>>>(xin, conv_w, conv_b, xc);
    k_xproj<<<dim3(8192), dim3(256), 0, stream>>>(xc, W_x, W_dt, b_dt, dtp, Bm, Cm);
    k_scanA<<<dim3(256), dim3(512), 0, stream>>>(dtp, xc, Bm, A_log, Sst, sdt);
    k_comb<<<dim3(64), dim3(256), 0, stream>>>(Sst, sdt, A_log, hinit);
    k_scanC<<<dim3(256), dim3(512), 0, stream>>>(dtp, xc, Bm, Cm, A_log, hinit,
                                                 D_skip, z, yact);
    k_gemm3<<<dim3(64, 4), dim3(256), 0, stream>>>(yact, W_out, out);
}

// Round 2
// 306.347 us; speedup vs baseline: 1.0967x; 1.0967x over previous
//
#include <hip/hip_runtime.h>
#include <math.h>

#define BSZ 2
#define CDIM 256
#define LSEQ 4096
#define DIN 512
#define NST 16
#define NC 128
#define CT 32
#define LOG2E 1.44269504088896f

typedef unsigned short ushort_t;
typedef short s16x8 __attribute__((ext_vector_type(8)));
typedef float f32x4 __attribute__((ext_vector_type(4)));

__device__ inline ushort_t f2bf(float f) {
    union { float f; unsigned u; } v; v.f = f;
    unsigned r = v.u + 0x7FFF + ((v.u >> 16) & 1);
    return (ushort_t)(r >> 16);
}

// ---------------- transpose + fp32->bf16 convert: dst[c][r] = src[r][c] ----
__global__ __launch_bounds__(256) void k_tconv(const float* __restrict__ src,
                                               ushort_t* __restrict__ dst,
                                               int R, int C) {
    __shared__ float T[32][33];
    int c0 = blockIdx.x * 32, r0 = blockIdx.y * 32;
    int tx = threadIdx.x & 31, ty = threadIdx.x >> 5;
    #pragma unroll
    for (int i = 0; i < 4; ++i)
        T[ty + i * 8][tx] = src[(r0 + ty + i * 8) * C + c0 + tx];
    __syncthreads();
    #pragma unroll
    for (int i = 0; i < 4; ++i)
        dst[(c0 + ty + i * 8) * R + r0 + tx] = f2bf(T[tx][ty + i * 8]);
}

// ---------------- LayerNorm -> bf16 (B,L,C) ----------------
__global__ __launch_bounds__(256) void k_ln(const float* __restrict__ x,
                                            const float* __restrict__ g,
                                            const float* __restrict__ beta,
                                            ushort_t* __restrict__ xsb) {
    int b  = blockIdx.x >> 7;
    int l0 = (blockIdx.x & 127) * 32;
    int tid = threadIdx.x;
    __shared__ float T[256][33];
    __shared__ float ps[8][32], ps2[8][32];
    __shared__ float mus[32], rs[32];
    #pragma unroll
    for (int i = 0; i < 8; ++i) {
        int f = i * 256 + tid;
        int c = f >> 3, lq = f & 7;
        float4 v = *(const float4*)(x + (b * 256 + c) * 4096 + l0 + lq * 4);
        T[c][lq * 4 + 0] = v.x; T[c][lq * 4 + 1] = v.y;
        T[c][lq * 4 + 2] = v.z; T[c][lq * 4 + 3] = v.w;
    }
    __syncthreads();
    {
        int lt = tid & 31, q = tid >> 5;
        float s = 0.f, s2 = 0.f;
        #pragma unroll
        for (int c = q * 32; c < q * 32 + 32; ++c) {
            float v = T[c][lt];
            s += v; s2 += v * v;
        }
        ps[q][lt] = s; ps2[q][lt] = s2;
    }
    __syncthreads();
    if (tid < 32) {
        float ts = 0.f, ts2 = 0.f;
        #pragma unroll
        for (int q = 0; q < 8; ++q) { ts += ps[q][tid]; ts2 += ps2[q][tid]; }
        float mu  = ts * (1.f / 256.f);
        float var = ts2 * (1.f / 256.f) - mu * mu;
        mus[tid] = mu;
        rs[tid]  = rsqrtf(var + 1e-5f);
    }
    __syncthreads();
    float gg = g[tid], bb = beta[tid];
    #pragma unroll
    for (int i = 0; i < 32; ++i) {
        float v = (T[tid][i] - mus[i]) * rs[i] * gg + bb;
        xsb[(b * 4096 + l0 + i) * 256 + tid] = f2bf(v);
    }
}

// ---------------- GEMM1 (MFMA bf16): xz = xs @ W_in ----------------
// A: (8192,256) bf16 row-major. Wt: (1024,256) bf16 (W_in transposed: row n = k-vector).
// BM=BN=128, BK=32. 4 waves in 2x2, each wave 64x64 via 4x4 grid of 16x16x32.
__global__ __launch_bounds__(256) void k_gemm1(const ushort_t* __restrict__ Abf,
                                               const ushort_t* __restrict__ Wt,
                                               float* __restrict__ xin,
                                               float* __restrict__ zout) {
    __shared__ ushort_t As[128][40];
    __shared__ ushort_t Bs[128][40];
    int tid = threadIdx.x;
    int m0 = blockIdx.x * 128;
    int n0 = blockIdx.y * 128;
    int lane = tid & 63, w = tid >> 6;
    int wr = w >> 1, wc = w & 1;
    int quad = lane >> 4, lm = lane & 15;
    f32x4 acc[4][4] = {};
    for (int k0 = 0; k0 < 256; k0 += 32) {
        #pragma unroll
        for (int i = 0; i < 2; ++i) {
            int c = i * 256 + tid;           // 512 chunks of 8 bf16
            int r = c >> 2, kq = c & 3;
            *(uint4*)&As[r][kq * 8] = *(const uint4*)&Abf[(m0 + r) * 256 + k0 + kq * 8];
            *(uint4*)&Bs[r][kq * 8] = *(const uint4*)&Wt[(n0 + r) * 256 + k0 + kq * 8];
        }
        __syncthreads();
        s16x8 af[4], bf_[4];
        #pragma unroll
        for (int mi = 0; mi < 4; ++mi)
            af[mi] = *(const s16x8*)&As[wr * 64 + mi * 16 + lm][quad * 8];
        #pragma unroll
        for (int ni = 0; ni < 4; ++ni)
            bf_[ni] = *(const s16x8*)&Bs[wc * 64 + ni * 16 + lm][quad * 8];
        #pragma unroll
        for (int mi = 0; mi < 4; ++mi)
            #pragma unroll
            for (int ni = 0; ni < 4; ++ni)
                acc[mi][ni] = __builtin_amdgcn_mfma_f32_16x16x32_bf16(
                    af[mi], bf_[ni], acc[mi][ni], 0, 0, 0);
        __syncthreads();
    }
    bool isz = (n0 >= 512);
    float* out = isz ? zout : xin;
    int nb = isz ? n0 - 512 : n0;
    #pragma unroll
    for (int mi = 0; mi < 4; ++mi) {
        #pragma unroll
        for (int ni = 0; ni < 4; ++ni) {
            int colg = nb + wc * 64 + ni * 16 + lm;
            #pragma unroll
            for (int r = 0; r < 4; ++r) {
                int rowg = m0 + wr * 64 + mi * 16 + quad * 4 + r;
                out[rowg * 512 + colg] = acc[mi][ni][r];
            }
        }
    }
}

// ---------------- depthwise causal conv(4) + SiLU ----------------
__global__ __launch_bounds__(256) void k_conv(const float* __restrict__ xin,
                                              const float* __restrict__ cw,
                                              const float* __restrict__ cb,
                                              float* __restrict__ xc) {
    int idx = blockIdx.x * 256 + threadIdx.x;
    int d = idx & 511;
    int r = idx >> 9;
    int l = r & 4095;
    int b = r >> 12;
    float s = cb[d];
    #pragma unroll
    for (int k = 0; k < 4; ++k) {
        int ll = l - 3 + k;
        if (ll >= 0) s += cw[d * 4 + k] * xin[(((b << 12) + ll) << 9) + d];
    }
    float sig = 1.f / (1.f + expf(-s));
    xc[idx] = s * sig;
}

// ---------------- x-proj GEMM (M=8192,N=48,K=512) + fused dt-proj ----------
// BM=64 tokens/block, 128 blocks.
__global__ __launch_bounds__(256) void k_xproj(const float* __restrict__ xc,
                                               const float* __restrict__ Wx,
                                               const float* __restrict__ Wdt,
                                               const float* __restrict__ bdt,
                                               float* __restrict__ dtp,
                                               float* __restrict__ Bm,
                                               float* __restrict__ Cm) {
    __shared__ float As[32][68];       // [k][token]
    __shared__ float Bs[32 * 48];      // [k][n] flat
    __shared__ float dbl[64][49];
    __shared__ float sWdt[16][512];
    int tid = threadIdx.x;
    int m0 = blockIdx.x * 64;
    // stage W_dt once
    #pragma unroll
    for (int i = 0; i < 32; ++i)
        ((float*)sWdt)[i * 256 + tid] = Wdt[i * 256 + tid];
    int tm = tid >> 4, tn = tid & 15;
    float acc[4][3] = {};
    for (int k0 = 0; k0 < 512; k0 += 32) {
        #pragma unroll
        for (int i = 0; i < 2; ++i) {
            int c = i * 256 + tid;         // 512 float4 chunks
            int r = c >> 3, kq = c & 7;
            float4 v = *(const float4*)(xc + (m0 + r) * 512 + k0 + kq * 4);
            As[kq * 4 + 0][r] = v.x; As[kq * 4 + 1][r] = v.y;
            As[kq * 4 + 2][r] = v.z; As[kq * 4 + 3][r] = v.w;
        }
        #pragma unroll
        for (int i = 0; i < 6; ++i) {
            int f = i * 256 + tid;         // 1536 floats
            Bs[f] = Wx[k0 * 48 + f];
        }
        __syncthreads();
        #pragma unroll
        for (int kk = 0; kk < 32; ++kk) {
            float4 a4 = *(float4*)&As[kk][tm * 4];
            float a[4] = {a4.x, a4.y, a4.z, a4.w};
            float bb[3];
            #pragma unroll
            for (int j = 0; j < 3; ++j) bb[j] = Bs[kk * 48 + tn * 3 + j];
            #pragma unroll
            for (int i = 0; i < 4; ++i)
                #pragma unroll
                for (int j = 0; j < 3; ++j)
                    acc[i][j] += a[i] * bb[j];
        }
        __syncthreads();
    }
    #pragma unroll
    for (int i = 0; i < 4; ++i) {
        int row = tm * 4 + i;
        #pragma unroll
        for (int j = 0; j < 3; ++j) {
            int col = tn * 3 + j;
            dbl[row][col] = acc[i][j];
            int tok = m0 + row;
            if (col >= 32)      Cm[tok * 16 + col - 32] = acc[i][j];
            else if (col >= 16) Bm[tok * 16 + col - 16] = acc[i][j];
        }
    }
    __syncthreads();
    float b0 = bdt[tid], b1 = bdt[tid + 256];
    for (int row = 0; row < 64; ++row) {
        float s0 = b0, s1 = b1;
        #pragma unroll
        for (int r = 0; r < 16; ++r) {
            float dv = dbl[row][r];
            s0 += dv * sWdt[r][tid];
            s1 += dv * sWdt[r][tid + 256];
        }
        s0 = (s0 > 20.f) ? s0 : log1pf(expf(s0));
        s1 = (s1 > 20.f) ? s1 : log1pf(expf(s1));
        int base = (m0 + row) * 512;
        dtp[base + tid] = s0;
        dtp[base + tid + 256] = s1;
    }
}

// ---------------- scan phase A ----------------
__global__ __launch_bounds__(512) void k_scanA(const float* __restrict__ dtp,
                                               const float* __restrict__ xc,
                                               const float* __restrict__ Bm,
                                               const float* __restrict__ A_log,
                                               float* __restrict__ S,
                                               float* __restrict__ sdt) {
    int b = blockIdx.x >> 7;
    int ch = blockIdx.x & 127;
    int d = threadIdx.x;
    __shared__ float Bb[CT][16];
    {
        int t = threadIdx.x >> 4, n = threadIdx.x & 15;
        Bb[t][n] = Bm[((b << 12) + ch * CT + t) * 16 + n];
    }
    __syncthreads();
    float a2[16];
    #pragma unroll
    for (int n = 0; n < 16; ++n) a2[n] = -expf(A_log[d * 16 + n]) * LOG2E;
    float h[16] = {};
    float sum_dt = 0.f;
    int base = ((b << 12) + ch * CT) * 512 + d;
    for (int t = 0; t < CT; ++t) {
        float dv = dtp[base + t * 512];
        float xv = xc[base + t * 512];
        sum_dt += dv;
        float dx = dv * xv;
        #pragma unroll
        for (int n = 0; n < 16; ++n) {
            float w = exp2f(dv * a2[n]);
            h[n] = w * h[n] + dx * Bb[t][n];
        }
    }
    int so = ((b * NC + ch) * 512 + d) * 16;
    #pragma unroll
    for (int n = 0; n < 16; n += 4)
        *(float4*)&S[so + n] = make_float4(h[n], h[n + 1], h[n + 2], h[n + 3]);
    sdt[(b * NC + ch) * 512 + d] = sum_dt;
}

// ---------------- scan phase B: in-place (hinit aliases S) ----------------
__global__ __launch_bounds__(256) void k_comb(float* S,    // read S, write hinit in place
                                              const float* __restrict__ sdt,
                                              const float* __restrict__ A_log) {
    int gidx = blockIdx.x * 256 + threadIdx.x;
    int n = gidx & 15;
    int d = (gidx >> 4) & 511;
    int b = gidx >> 13;
    float a2 = -expf(A_log[d * 16 + n]) * LOG2E;
    float h = 0.f;
    #pragma unroll 4
    for (int c = 0; c < NC; ++c) {
        int ci = (b * NC + c) * 512 + d;
        float w = exp2f(a2 * sdt[ci]);
        float sval = S[ci * 16 + n];   // load BEFORE overwrite (alias-safe)
        S[ci * 16 + n] = h;
        h = w * h + sval;
    }
}

// ---------------- scan phase C: replay + skip + SiLU gate -> bf16 ----------
__global__ __launch_bounds__(512) void k_scanC(const float* __restrict__ dtp,
                                               const float* __restrict__ xc,
                                               const float* __restrict__ Bm,
                                               const float* __restrict__ Cm,
                                               const float* __restrict__ A_log,
                                               const float* __restrict__ hinit,
                                               const float* __restrict__ Dskip,
                                               const float* __restrict__ zin,
                                               ushort_t* __restrict__ yact) {
    int b = blockIdx.x >> 7;
    int ch = blockIdx.x & 127;
    int d = threadIdx.x;
    __shared__ float Bb[CT][16], Cb[CT][16];
    {
        int t = threadIdx.x >> 4, n = threadIdx.x & 15;
        int li = ((b << 12) + ch * CT + t) * 16 + n;
        Bb[t][n] = Bm[li];
        Cb[t][n] = Cm[li];
    }
    __syncthreads();
    float a2[16], h[16];
    #pragma unroll
    for (int n = 0; n < 16; ++n) a2[n] = -expf(A_log[d * 16 + n]) * LOG2E;
    int hi = ((b * NC + ch) * 512 + d) * 16;
    #pragma unroll
    for (int n = 0; n < 16; n += 4) {
        float4 v = *(const float4*)&hinit[hi + n];
        h[n] = v.x; h[n + 1] = v.y; h[n + 2] = v.z; h[n + 3] = v.w;
    }
    float Dsk = Dskip[d];
    int base = ((b << 12) + ch * CT) * 512 + d;
    for (int t = 0; t < CT; ++t) {
        float dv = dtp[base + t * 512];
        float xv = xc[base + t * 512];
        float zv = zin[base + t * 512];
        float dx = dv * xv;
        float y = 0.f;
        #pragma unroll
        for (int n = 0; n < 16; ++n) {
            float w = exp2f(dv * a2[n]);
            h[n] = w * h[n] + dx * Bb[t][n];
            y += h[n] * Cb[t][n];
        }
        y += xv * Dsk;
        float sig = 1.f / (1.f + expf(-zv));
        yact[base + t * 512] = f2bf(y * zv * sig);
    }
}

// ---------------- GEMM3 (MFMA bf16): out = yact @ W_out, transposed store ---
// A: (8192,512) bf16. Wt3: (256,512) bf16. BM=128, BN=64, BK=32.
__global__ __launch_bounds__(256) void k_gemm3(const ushort_t* __restrict__ Abf,
                                               const ushort_t* __restrict__ Wt3,
                                               float* __restrict__ out) {
    __shared__ ushort_t As[128][40];
    __shared__ ushort_t Bs[64][40];
    __shared__ float T[64][132];
    int tid = threadIdx.x;
    int m0 = blockIdx.x * 128;
    int n0 = blockIdx.y * 64;
    int lane = tid & 63, w = tid >> 6;
    int wr = w >> 1, wc = w & 1;
    int quad = lane >> 4, lm = lane & 15;
    f32x4 acc[4][2] = {};
    for (int k0 = 0; k0 < 512; k0 += 32) {
        #pragma unroll
        for (int i = 0; i < 2; ++i) {
            int c = i * 256 + tid;
            int r = c >> 2, kq = c & 3;
            *(uint4*)&As[r][kq * 8] = *(const uint4*)&Abf[(m0 + r) * 512 + k0 + kq * 8];
        }
        {
            int r = tid >> 2, kq = tid & 3;
            *(uint4*)&Bs[r][kq * 8] = *(const uint4*)&Wt3[(n0 + r) * 512 + k0 + kq * 8];
        }
        __syncthreads();
        s16x8 af[4], bf_[2];
        #pragma unroll
        for (int mi = 0; mi < 4; ++mi)
            af[mi] = *(const s16x8*)&As[wr * 64 + mi * 16 + lm][quad * 8];
        #pragma unroll
        for (int ni = 0; ni < 2; ++ni)
            bf_[ni] = *(const s16x8*)&Bs[wc * 32 + ni * 16 + lm][quad * 8];
        #pragma unroll
        for (int mi = 0; mi < 4; ++mi)
            #pragma unroll
            for (int ni = 0; ni < 2; ++ni)
                acc[mi][ni] = __builtin_amdgcn_mfma_f32_16x16x32_bf16(
                    af[mi], bf_[ni], acc[mi][ni], 0, 0, 0);
        __syncthreads();
    }
    #pragma unroll
    for (int mi = 0; mi < 4; ++mi)
        #pragma unroll
        for (int ni = 0; ni < 2; ++ni)
            #pragma unroll
            for (int r = 0; r < 4; ++r)
                T[wc * 32 + ni * 16 + lm][wr * 64 + mi * 16 + quad * 4 + r] = acc[mi][ni][r];
    __syncthreads();
    int b = m0 >> 12;
    int l0 = m0 & 4095;
    #pragma unroll
    for (int i = 0; i < 8; ++i) {
        int f = i * 256 + tid;
        int col = f >> 5, lq = f & 31;
        float4 v = *(float4*)&T[col][lq * 4];
        *(float4*)(out + b * (256 * 4096) + (n0 + col) * 4096 + l0 + lq * 4) = v;
    }
}

extern "C" void kernel_launch(void* const* d_in, const int* in_sizes, int n_in,
                              void* d_out, int out_size, void* d_ws, size_t ws_size,
                              hipStream_t stream) {
    const float* x      = (const float*)d_in[0];
    const float* ln_g   = (const float*)d_in[1];
    const float* ln_b   = (const float*)d_in[2];
    const float* W_in   = (const float*)d_in[3];
    const float* conv_w = (const float*)d_in[4];
    const float* conv_b = (const float*)d_in[5];
    const float* W_x    = (const float*)d_in[6];
    const float* W_dt   = (const float*)d_in[7];
    const float* b_dt   = (const float*)d_in[8];
    const float* A_log  = (const float*)d_in[9];
    const float* D_skip = (const float*)d_in[10];
    const float* W_out  = (const float*)d_in[11];
    float* out = (float*)d_out;

    float* ws = (float*)d_ws;
    float* xin = ws;                       // 4,194,304 f
    float* z   = xin + 4194304;            // 4,194,304 f
    float* xc  = z   + 4194304;            // 4,194,304 f
    float* dtp = xc  + 4194304;            // 4,194,304 f
    float* Bm  = dtp + 4194304;            // 131,072 f
    float* Cm  = Bm  + 131072;             // 131,072 f
    float* Sst = Cm  + 131072;             // 2,097,152 f (hinit aliases, in-place)
    float* sdt = Sst + 2097152;            // 131,072 f
    ushort_t* xs_bf = (ushort_t*)(sdt + 131072);   // 2,097,152 bf16
    ushort_t* Wt1   = xs_bf + 2097152;             // 262,144 bf16
    ushort_t* Wt3   = Wt1 + 262144;                // 131,072 bf16
    ushort_t* yact  = (ushort_t*)xin;              // alias xin (dead after conv)

    k_tconv<<<dim3(32, 8),  dim3(256), 0, stream>>>(W_in,  Wt1, 256, 1024);
    k_tconv<<<dim3(8, 16),  dim3(256), 0, stream>>>(W_out, Wt3, 512, 256);
    k_ln   <<<dim3(256),    dim3(256), 0, stream>>>(x, ln_g, ln_b, xs_bf);
    k_gemm1<<<dim3(64, 8),  dim3(256), 0, stream>>>(xs_bf, Wt1, xin, z);
    k_conv <<<dim3(16384),  dim3(256), 0, stream>>>(xin, conv_w, conv_b, xc);
    k_xproj<<<dim3(128),    dim3(256), 0, stream>>>(xc, W_x, W_dt, b_dt, dtp, Bm, Cm);
    k_scanA<<<dim3(256),    dim3(512), 0, stream>>>(dtp, xc, Bm, A_log, Sst, sdt);
    k_comb <<<dim3(64),     dim3(256), 0, stream>>>(Sst, sdt, A_log);
    k_scanC<<<dim3(256),    dim3(512), 0, stream>>>(dtp, xc, Bm, Cm, A_log, Sst,
                                                    D_skip, z, yact);
    k_gemm3<<<dim3(64, 4),  dim3(256), 0, stream>>>(yact, Wt3, out);
}

// Round 3
// 243.210 us; speedup vs baseline: 1.3814x; 1.2596x over previous
//
#include <hip/hip_runtime.h>
#include <math.h>

#define BSZ 2
#define CDIM 256
#define LSEQ 4096
#define DIN 512
#define NST 16
#define NC 128
#define CT 32
#define LOG2E 1.44269504088896f

typedef unsigned short ushort_t;
typedef short s16x8 __attribute__((ext_vector_type(8)));
typedef float f32x4 __attribute__((ext_vector_type(4)));

__device__ inline ushort_t f2bf(float f) {
    union { float f; unsigned u; } v; v.f = f;
    unsigned r = v.u + 0x7FFF + ((v.u >> 16) & 1);
    return (ushort_t)(r >> 16);
}

// ---------------- transpose + fp32->bf16 convert: dst[c][r] = src[r][c] ----
__global__ __launch_bounds__(256) void k_tconv(const float* __restrict__ src,
                                               ushort_t* __restrict__ dst,
                                               int R, int C) {
    __shared__ float T[32][33];
    int c0 = blockIdx.x * 32, r0 = blockIdx.y * 32;
    int tx = threadIdx.x & 31, ty = threadIdx.x >> 5;
    #pragma unroll
    for (int i = 0; i < 4; ++i)
        T[ty + i * 8][tx] = src[(r0 + ty + i * 8) * C + c0 + tx];
    __syncthreads();
    #pragma unroll
    for (int i = 0; i < 4; ++i)
        dst[(c0 + ty + i * 8) * R + r0 + tx] = f2bf(T[tx][ty + i * 8]);
}

// ---------------- W_x (512,48) -> Wxt (48,512) bf16 ----------------
__global__ __launch_bounds__(256) void k_wxt(const float* __restrict__ src,
                                             ushort_t* __restrict__ dst) {
    int n = blockIdx.x;          // 48 rows
    int tid = threadIdx.x;
    dst[n * 512 + tid]       = f2bf(src[tid * 48 + n]);
    dst[n * 512 + 256 + tid] = f2bf(src[(256 + tid) * 48 + n]);
}

// ---------------- LayerNorm -> bf16 (B,L,C) ----------------
__global__ __launch_bounds__(256) void k_ln(const float* __restrict__ x,
                                            const float* __restrict__ g,
                                            const float* __restrict__ beta,
                                            ushort_t* __restrict__ xsb) {
    int b  = blockIdx.x >> 7;
    int l0 = (blockIdx.x & 127) * 32;
    int tid = threadIdx.x;
    __shared__ float T[256][33];
    __shared__ float ps[8][32], ps2[8][32];
    __shared__ float mus[32], rs[32];
    #pragma unroll
    for (int i = 0; i < 8; ++i) {
        int f = i * 256 + tid;
        int c = f >> 3, lq = f & 7;
        float4 v = *(const float4*)(x + (b * 256 + c) * 4096 + l0 + lq * 4);
        T[c][lq * 4 + 0] = v.x; T[c][lq * 4 + 1] = v.y;
        T[c][lq * 4 + 2] = v.z; T[c][lq * 4 + 3] = v.w;
    }
    __syncthreads();
    {
        int lt = tid & 31, q = tid >> 5;
        float s = 0.f, s2 = 0.f;
        #pragma unroll
        for (int c = q * 32; c < q * 32 + 32; ++c) {
            float v = T[c][lt];
            s += v; s2 += v * v;
        }
        ps[q][lt] = s; ps2[q][lt] = s2;
    }
    __syncthreads();
    if (tid < 32) {
        float ts = 0.f, ts2 = 0.f;
        #pragma unroll
        for (int q = 0; q < 8; ++q) { ts += ps[q][tid]; ts2 += ps2[q][tid]; }
        float mu  = ts * (1.f / 256.f);
        float var = ts2 * (1.f / 256.f) - mu * mu;
        mus[tid] = mu;
        rs[tid]  = rsqrtf(var + 1e-5f);
    }
    __syncthreads();
    float gg = g[tid], bb = beta[tid];
    #pragma unroll
    for (int i = 0; i < 32; ++i) {
        float v = (T[tid][i] - mus[i]) * rs[i] * gg + bb;
        xsb[(b * 4096 + l0 + i) * 256 + tid] = f2bf(v);
    }
}

// ---------------- GEMM1 (MFMA bf16): xz = xs @ W_in ----------------
__global__ __launch_bounds__(256) void k_gemm1(const ushort_t* __restrict__ Abf,
                                               const ushort_t* __restrict__ Wt,
                                               float* __restrict__ xin,
                                               float* __restrict__ zout) {
    __shared__ ushort_t As[128][40];
    __shared__ ushort_t Bs[128][40];
    int tid = threadIdx.x;
    int m0 = blockIdx.x * 128;
    int n0 = blockIdx.y * 128;
    int lane = tid & 63, w = tid >> 6;
    int wr = w >> 1, wc = w & 1;
    int quad = lane >> 4, lm = lane & 15;
    f32x4 acc[4][4] = {};
    for (int k0 = 0; k0 < 256; k0 += 32) {
        #pragma unroll
        for (int i = 0; i < 2; ++i) {
            int c = i * 256 + tid;
            int r = c >> 2, kq = c & 3;
            *(uint4*)&As[r][kq * 8] = *(const uint4*)&Abf[(m0 + r) * 256 + k0 + kq * 8];
            *(uint4*)&Bs[r][kq * 8] = *(const uint4*)&Wt[(n0 + r) * 256 + k0 + kq * 8];
        }
        __syncthreads();
        s16x8 af[4], bf_[4];
        #pragma unroll
        for (int mi = 0; mi < 4; ++mi)
            af[mi] = *(const s16x8*)&As[wr * 64 + mi * 16 + lm][quad * 8];
        #pragma unroll
        for (int ni = 0; ni < 4; ++ni)
            bf_[ni] = *(const s16x8*)&Bs[wc * 64 + ni * 16 + lm][quad * 8];
        #pragma unroll
        for (int mi = 0; mi < 4; ++mi)
            #pragma unroll
            for (int ni = 0; ni < 4; ++ni)
                acc[mi][ni] = __builtin_amdgcn_mfma_f32_16x16x32_bf16(
                    af[mi], bf_[ni], acc[mi][ni], 0, 0, 0);
        __syncthreads();
    }
    bool isz = (n0 >= 512);
    float* out = isz ? zout : xin;
    int nb = isz ? n0 - 512 : n0;
    #pragma unroll
    for (int mi = 0; mi < 4; ++mi) {
        #pragma unroll
        for (int ni = 0; ni < 4; ++ni) {
            int colg = nb + wc * 64 + ni * 16 + lm;
            #pragma unroll
            for (int r = 0; r < 4; ++r) {
                int rowg = m0 + wr * 64 + mi * 16 + quad * 4 + r;
                out[rowg * 512 + colg] = acc[mi][ni][r];
            }
        }
    }
}

// ---------------- depthwise causal conv(4) + SiLU (fp32 + bf16 out) --------
__global__ __launch_bounds__(256) void k_conv(const float* __restrict__ xin,
                                              const float* __restrict__ cw,
                                              const float* __restrict__ cb,
                                              float* __restrict__ xc,
                                              ushort_t* __restrict__ xcb) {
    int idx = blockIdx.x * 256 + threadIdx.x;
    int d = idx & 511;
    int r = idx >> 9;
    int l = r & 4095;
    int b = r >> 12;
    float s = cb[d];
    #pragma unroll
    for (int k = 0; k < 4; ++k) {
        int ll = l - 3 + k;
        if (ll >= 0) s += cw[d * 4 + k] * xin[(((b << 12) + ll) << 9) + d];
    }
    float sig = 1.f / (1.f + expf(-s));
    float v = s * sig;
    xc[idx] = v;
    xcb[idx] = f2bf(v);
}

// ---------------- x-proj (MFMA): dbl = xc @ W_x -> dtr/Bm/Cm ---------------
// A: xcb (8192,512) bf16. B: Wxt (48,512) bf16. BM=64, BN=48, BK=64, grid 128.
__global__ __launch_bounds__(256) void k_xproj1(const ushort_t* __restrict__ xcb,
                                                const ushort_t* __restrict__ Wxt,
                                                float* __restrict__ dtr,
                                                float* __restrict__ Bm,
                                                float* __restrict__ Cm) {
    __shared__ ushort_t As[64][72];
    __shared__ ushort_t Bs[48][72];
    int tid = threadIdx.x;
    int m0 = blockIdx.x * 64;
    int lane = tid & 63, w = tid >> 6;
    int quad = lane >> 4, lm = lane & 15;
    f32x4 acc[3] = {};
    for (int k0 = 0; k0 < 512; k0 += 64) {
        #pragma unroll
        for (int i = 0; i < 2; ++i) {
            int f = i * 256 + tid;          // 512 chunks (64 rows x 8)
            int r = f >> 3, kq = f & 7;
            *(uint4*)&As[r][kq * 8] = *(const uint4*)&xcb[(m0 + r) * 512 + k0 + kq * 8];
        }
        if (tid < 192) {
            #pragma unroll
            for (int i = 0; i < 2; ++i) {
                int f = i * 192 + tid;      // 384 chunks (48 rows x 8)
                int r = f >> 3, kq = f & 7;
                *(uint4*)&Bs[r][kq * 8] = *(const uint4*)&Wxt[r * 512 + k0 + kq * 8];
            }
        }
        __syncthreads();
        #pragma unroll
        for (int kk = 0; kk < 2; ++kk) {
            s16x8 af = *(const s16x8*)&As[w * 16 + lm][kk * 32 + quad * 8];
            #pragma unroll
            for (int nt = 0; nt < 3; ++nt) {
                s16x8 bv = *(const s16x8*)&Bs[nt * 16 + lm][kk * 32 + quad * 8];
                acc[nt] = __builtin_amdgcn_mfma_f32_16x16x32_bf16(af, bv, acc[nt], 0, 0, 0);
            }
        }
        __syncthreads();
    }
    #pragma unroll
    for (int nt = 0; nt < 3; ++nt) {
        float* dst = (nt == 0) ? dtr : ((nt == 1) ? Bm : Cm);
        #pragma unroll
        for (int r = 0; r < 4; ++r) {
            int row = m0 + w * 16 + quad * 4 + r;
            dst[row * 16 + lm] = acc[nt][r];
        }
    }
}

// ---------------- dt-proj: dtp = softplus(dtr @ W_dt + b_dt) ----------------
__global__ __launch_bounds__(256) void k_dtproj(const float* __restrict__ dtr,
                                                const float* __restrict__ Wdt,
                                                const float* __restrict__ bdt,
                                                float* __restrict__ dtp) {
    int tid = threadIdx.x;
    int t0 = blockIdx.x * 16;
    __shared__ float R[16][17];
    float w0[16], w1[16];
    #pragma unroll
    for (int r = 0; r < 16; ++r) {
        w0[r] = Wdt[r * 512 + tid];
        w1[r] = Wdt[r * 512 + 256 + tid];
    }
    float b0 = bdt[tid], b1 = bdt[256 + tid];
    {
        int t = tid >> 4, r = tid & 15;
        R[t][r] = dtr[(t0 + t) * 16 + r];
    }
    __syncthreads();
    for (int t = 0; t < 16; ++t) {
        float s0 = b0, s1 = b1;
        #pragma unroll
        for (int r = 0; r < 16; ++r) {
            float dv = R[t][r];
            s0 += dv * w0[r];
            s1 += dv * w1[r];
        }
        s0 = (s0 > 20.f) ? s0 : log1pf(expf(s0));
        s1 = (s1 > 20.f) ? s1 : log1pf(expf(s1));
        dtp[(t0 + t) * 512 + tid] = s0;
        dtp[(t0 + t) * 512 + 256 + tid] = s1;
    }
}

// ---------------- scan phase A ----------------
__global__ __launch_bounds__(512) void k_scanA(const float* __restrict__ dtp,
                                               const float* __restrict__ xc,
                                               const float* __restrict__ Bm,
                                               const float* __restrict__ A_log,
                                               float* __restrict__ S,
                                               float* __restrict__ sdt) {
    int b = blockIdx.x >> 7;
    int ch = blockIdx.x & 127;
    int d = threadIdx.x;
    __shared__ float Bb[CT][16];
    {
        int t = threadIdx.x >> 4, n = threadIdx.x & 15;
        Bb[t][n] = Bm[((b << 12) + ch * CT + t) * 16 + n];
    }
    __syncthreads();
    float a2[16];
    #pragma unroll
    for (int n = 0; n < 16; ++n) a2[n] = -expf(A_log[d * 16 + n]) * LOG2E;
    float h[16] = {};
    float sum_dt = 0.f;
    int base = ((b << 12) + ch * CT) * 512 + d;
    for (int t = 0; t < CT; ++t) {
        float dv = dtp[base + t * 512];
        float xv = xc[base + t * 512];
        sum_dt += dv;
        float dx = dv * xv;
        #pragma unroll
        for (int n = 0; n < 16; ++n) {
            float w = exp2f(dv * a2[n]);
            h[n] = w * h[n] + dx * Bb[t][n];
        }
    }
    int so = ((b * NC + ch) * 512 + d) * 16;
    #pragma unroll
    for (int n = 0; n < 16; n += 4)
        *(float4*)&S[so + n] = make_float4(h[n], h[n + 1], h[n + 2], h[n + 3]);
    sdt[(b * NC + ch) * 512 + d] = sum_dt;
}

// ---------------- scan phase B: in-place (hinit aliases S) ----------------
__global__ __launch_bounds__(256) void k_comb(float* S,
                                              const float* __restrict__ sdt,
                                              const float* __restrict__ A_log) {
    int gidx = blockIdx.x * 256 + threadIdx.x;
    int n = gidx & 15;
    int d = (gidx >> 4) & 511;
    int b = gidx >> 13;
    float a2 = -expf(A_log[d * 16 + n]) * LOG2E;
    float h = 0.f;
    #pragma unroll 4
    for (int c = 0; c < NC; ++c) {
        int ci = (b * NC + c) * 512 + d;
        float w = exp2f(a2 * sdt[ci]);
        float sval = S[ci * 16 + n];
        S[ci * 16 + n] = h;
        h = w * h + sval;
    }
}

// ---------------- scan phase C ----------------
__global__ __launch_bounds__(512) void k_scanC(const float* __restrict__ dtp,
                                               const float* __restrict__ xc,
                                               const float* __restrict__ Bm,
                                               const float* __restrict__ Cm,
                                               const float* __restrict__ A_log,
                                               const float* __restrict__ hinit,
                                               const float* __restrict__ Dskip,
                                               const float* __restrict__ zin,
                                               ushort_t* __restrict__ yact) {
    int b = blockIdx.x >> 7;
    int ch = blockIdx.x & 127;
    int d = threadIdx.x;
    __shared__ float Bb[CT][16], Cb[CT][16];
    {
        int t = threadIdx.x >> 4, n = threadIdx.x & 15;
        int li = ((b << 12) + ch * CT + t) * 16 + n;
        Bb[t][n] = Bm[li];
        Cb[t][n] = Cm[li];
    }
    __syncthreads();
    float a2[16], h[16];
    #pragma unroll
    for (int n = 0; n < 16; ++n) a2[n] = -expf(A_log[d * 16 + n]) * LOG2E;
    int hi = ((b * NC + ch) * 512 + d) * 16;
    #pragma unroll
    for (int n = 0; n < 16; n += 4) {
        float4 v = *(const float4*)&hinit[hi + n];
        h[n] = v.x; h[n + 1] = v.y; h[n + 2] = v.z; h[n + 3] = v.w;
    }
    float Dsk = Dskip[d];
    int base = ((b << 12) + ch * CT) * 512 + d;
    for (int t = 0; t < CT; ++t) {
        float dv = dtp[base + t * 512];
        float xv = xc[base + t * 512];
        float zv = zin[base + t * 512];
        float dx = dv * xv;
        float y = 0.f;
        #pragma unroll
        for (int n = 0; n < 16; ++n) {
            float w = exp2f(dv * a2[n]);
            h[n] = w * h[n] + dx * Bb[t][n];
            y += h[n] * Cb[t][n];
        }
        y += xv * Dsk;
        float sig = 1.f / (1.f + expf(-zv));
        yact[base + t * 512] = f2bf(y * zv * sig);
    }
}

// ---------------- GEMM3 (MFMA bf16) ----------------
__global__ __launch_bounds__(256) void k_gemm3(const ushort_t* __restrict__ Abf,
                                               const ushort_t* __restrict__ Wt3,
                                               float* __restrict__ out) {
    __shared__ ushort_t As[128][40];
    __shared__ ushort_t Bs[64][40];
    __shared__ float T[64][132];
    int tid = threadIdx.x;
    int m0 = blockIdx.x * 128;
    int n0 = blockIdx.y * 64;
    int lane = tid & 63, w = tid >> 6;
    int wr = w >> 1, wc = w & 1;
    int quad = lane >> 4, lm = lane & 15;
    f32x4 acc[4][2] = {};
    for (int k0 = 0; k0 < 512; k0 += 32) {
        #pragma unroll
        for (int i = 0; i < 2; ++i) {
            int c = i * 256 + tid;
            int r = c >> 2, kq = c & 3;
            *(uint4*)&As[r][kq * 8] = *(const uint4*)&Abf[(m0 + r) * 512 + k0 + kq * 8];
        }
        {
            int r = tid >> 2, kq = tid & 3;
            *(uint4*)&Bs[r][kq * 8] = *(const uint4*)&Wt3[(n0 + r) * 512 + k0 + kq * 8];
        }
        __syncthreads();
        s16x8 af[4], bf_[2];
        #pragma unroll
        for (int mi = 0; mi < 4; ++mi)
            af[mi] = *(const s16x8*)&As[wr * 64 + mi * 16 + lm][quad * 8];
        #pragma unroll
        for (int ni = 0; ni < 2; ++ni)
            bf_[ni] = *(const s16x8*)&Bs[wc * 32 + ni * 16 + lm][quad * 8];
        #pragma unroll
        for (int mi = 0; mi < 4; ++mi)
            #pragma unroll
            for (int ni = 0; ni < 2; ++ni)
                acc[mi][ni] = __builtin_amdgcn_mfma_f32_16x16x32_bf16(
                    af[mi], bf_[ni], acc[mi][ni], 0, 0, 0);
        __syncthreads();
    }
    #pragma unroll
    for (int mi = 0; mi < 4; ++mi)
        #pragma unroll
        for (int ni = 0; ni < 2; ++ni)
            #pragma unroll
            for (int r = 0; r < 4; ++r)
                T[wc * 32 + ni * 16 + lm][wr * 64 + mi * 16 + quad * 4 + r] = acc[mi][ni][r];
    __syncthreads();
    int b = m0 >> 12;
    int l0 = m0 & 4095;
    #pragma unroll
    for (int i = 0; i < 8; ++i) {
        int f = i * 256 + tid;
        int col = f >> 5, lq = f & 31;
        float4 v = *(float4*)&T[col][lq * 4];
        *(float4*)(out + b * (256 * 4096) + (n0 + col) * 4096 + l0 + lq * 4) = v;
    }
}

extern "C" void kernel_launch(void* const* d_in, const int* in_sizes, int n_in,
                              void* d_out, int out_size, void* d_ws, size_t ws_size,
                              hipStream_t stream) {
    const float* x      = (const float*)d_in[0];
    const float* ln_g   = (const float*)d_in[1];
    const float* ln_b   = (const float*)d_in[2];
    const float* W_in   = (const float*)d_in[3];
    const float* conv_w = (const float*)d_in[4];
    const float* conv_b = (const float*)d_in[5];
    const float* W_x    = (const float*)d_in[6];
    const float* W_dt   = (const float*)d_in[7];
    const float* b_dt   = (const float*)d_in[8];
    const float* A_log  = (const float*)d_in[9];
    const float* D_skip = (const float*)d_in[10];
    const float* W_out  = (const float*)d_in[11];
    float* out = (float*)d_out;

    float* ws = (float*)d_ws;
    float* xin = ws;                       // 4,194,304 f
    float* z   = xin + 4194304;            // 4,194,304 f
    float* xc  = z   + 4194304;            // 4,194,304 f
    float* dtp = xc  + 4194304;            // 4,194,304 f
    float* Bm  = dtp + 4194304;            // 131,072 f
    float* Cm  = Bm  + 131072;             // 131,072 f
    float* Sst = Cm  + 131072;             // 2,097,152 f (hinit aliases, in-place)
    float* sdt = Sst + 2097152;            // 131,072 f
    float* dtr = sdt + 131072;             // 131,072 f
    ushort_t* xs_bf = (ushort_t*)(dtr + 131072);   // 2,097,152 bf16
    ushort_t* Wt1   = xs_bf + 2097152;             // 262,144 bf16
    ushort_t* Wt3   = Wt1 + 262144;                // 131,072 bf16
    ushort_t* xcb   = Wt3 + 131072;                // 4,194,304 bf16
    ushort_t* Wxt   = xcb + 4194304;               // 24,576 bf16
    ushort_t* yact  = (ushort_t*)xin;              // alias xin (dead after conv)

    k_tconv <<<dim3(32, 8), dim3(256), 0, stream>>>(W_in,  Wt1, 256, 1024);
    k_tconv <<<dim3(8, 16), dim3(256), 0, stream>>>(W_out, Wt3, 512, 256);
    k_wxt   <<<dim3(48),    dim3(256), 0, stream>>>(W_x, Wxt);
    k_ln    <<<dim3(256),   dim3(256), 0, stream>>>(x, ln_g, ln_b, xs_bf);
    k_gemm1 <<<dim3(64, 8), dim3(256), 0, stream>>>(xs_bf, Wt1, xin, z);
    k_conv  <<<dim3(16384), dim3(256), 0, stream>>>(xin, conv_w, conv_b, xc, xcb);
    k_xproj1<<<dim3(128),   dim3(256), 0, stream>>>(xcb, Wxt, dtr, Bm, Cm);
    k_dtproj<<<dim3(512),   dim3(256), 0, stream>>>(dtr, W_dt, b_dt, dtp);
    k_scanA <<<dim3(256),   dim3(512), 0, stream>>>(dtp, xc, Bm, A_log, Sst, sdt);
    k_comb  <<<dim3(64),    dim3(256), 0, stream>>>(Sst, sdt, A_log);
    k_scanC <<<dim3(256),   dim3(512), 0, stream>>>(dtp, xc, Bm, Cm, A_log, Sst,
                                                    D_skip, z, yact);
    k_gemm3 <<<dim3(64, 4), dim3(256), 0, stream>>>(yact, Wt3, out);
}

// Round 4
// 229.974 us; speedup vs baseline: 1.4609x; 1.0576x over previous
//
#include <hip/hip_runtime.h>
#include <math.h>

#define BSZ 2
#define CDIM 256
#define LSEQ 4096
#define DIN 512
#define NST 16
#define NC 128
#define CT 32
#define LOG2E 1.44269504088896f

typedef unsigned short ushort_t;
typedef short s16x8 __attribute__((ext_vector_type(8)));
typedef float f32x4 __attribute__((ext_vector_type(4)));

__device__ inline ushort_t f2bf(float f) {
    union { float f; unsigned u; } v; v.f = f;
    unsigned r = v.u + 0x7FFF + ((v.u >> 16) & 1);
    return (ushort_t)(r >> 16);
}
__device__ inline float bf2f(ushort_t u) {
    union { unsigned u; float f; } v; v.u = ((unsigned)u) << 16;
    return v.f;
}

// ---------------- prep: all weight transposes/converts in one kernel -------
// bi 0..255   : W_in (256,1024) -> Wt1 (1024,256) bf16
// bi 256..383 : W_out (512,256) -> Wt3 (256,512) bf16
// bi 384..479 : W_x (512,48)    -> Wxt (48,512) bf16
__device__ inline void tile_tr(const float* __restrict__ src, ushort_t* __restrict__ dst,
                               int R, int C, int c0, int r0, int tid) {
    __shared__ float T[32][33];
    int tx = tid & 31, ty = tid >> 5;
    #pragma unroll
    for (int i = 0; i < 4; ++i)
        T[ty + i * 8][tx] = src[(r0 + ty + i * 8) * C + c0 + tx];
    __syncthreads();
    #pragma unroll
    for (int i = 0; i < 4; ++i)
        dst[(c0 + ty + i * 8) * R + r0 + tx] = f2bf(T[tx][ty + i * 8]);
}

__global__ __launch_bounds__(256) void k_prep(const float* __restrict__ W_in,
                                              const float* __restrict__ W_out,
                                              const float* __restrict__ W_x,
                                              ushort_t* __restrict__ Wt1,
                                              ushort_t* __restrict__ Wt3,
                                              ushort_t* __restrict__ Wxt) {
    int bi = blockIdx.x, tid = threadIdx.x;
    if (bi < 256) {
        tile_tr(W_in, Wt1, 256, 1024, (bi & 31) * 32, (bi >> 5) * 32, tid);
    } else if (bi < 384) {
        int rem = bi - 256;
        tile_tr(W_out, Wt3, 512, 256, (rem & 7) * 32, (rem >> 3) * 32, tid);
    } else {
        int f = (bi - 384) * 256 + tid;
        int n = f >> 9, dcol = f & 511;
        Wxt[n * 512 + dcol] = f2bf(W_x[dcol * 48 + n]);
    }
}

// ---------------- LayerNorm -> bf16 (B,L,C) ----------------
__global__ __launch_bounds__(256) void k_ln(const float* __restrict__ x,
                                            const float* __restrict__ g,
                                            const float* __restrict__ beta,
                                            ushort_t* __restrict__ xsb) {
    int b  = blockIdx.x >> 7;
    int l0 = (blockIdx.x & 127) * 32;
    int tid = threadIdx.x;
    __shared__ float T[256][33];
    __shared__ float ps[8][32], ps2[8][32];
    __shared__ float mus[32], rs[32];
    #pragma unroll
    for (int i = 0; i < 8; ++i) {
        int f = i * 256 + tid;
        int c = f >> 3, lq = f & 7;
        float4 v = *(const float4*)(x + (b * 256 + c) * 4096 + l0 + lq * 4);
        T[c][lq * 4 + 0] = v.x; T[c][lq * 4 + 1] = v.y;
        T[c][lq * 4 + 2] = v.z; T[c][lq * 4 + 3] = v.w;
    }
    __syncthreads();
    {
        int lt = tid & 31, q = tid >> 5;
        float s = 0.f, s2 = 0.f;
        #pragma unroll
        for (int c = q * 32; c < q * 32 + 32; ++c) {
            float v = T[c][lt];
            s += v; s2 += v * v;
        }
        ps[q][lt] = s; ps2[q][lt] = s2;
    }
    __syncthreads();
    if (tid < 32) {
        float ts = 0.f, ts2 = 0.f;
        #pragma unroll
        for (int q = 0; q < 8; ++q) { ts += ps[q][tid]; ts2 += ps2[q][tid]; }
        float mu  = ts * (1.f / 256.f);
        float var = ts2 * (1.f / 256.f) - mu * mu;
        mus[tid] = mu;
        rs[tid]  = rsqrtf(var + 1e-5f);
    }
    __syncthreads();
    float gg = g[tid], bb = beta[tid];
    #pragma unroll
    for (int i = 0; i < 32; ++i) {
        float v = (T[tid][i] - mus[i]) * rs[i] * gg + bb;
        xsb[(b * 4096 + l0 + i) * 256 + tid] = f2bf(v);
    }
}

// ---------------- GEMM1 (MFMA bf16): xz = xs @ W_in -> bf16 xin,z ----------
__global__ __launch_bounds__(256) void k_gemm1(const ushort_t* __restrict__ Abf,
                                               const ushort_t* __restrict__ Wt,
                                               ushort_t* __restrict__ xinb,
                                               ushort_t* __restrict__ zb) {
    __shared__ ushort_t As[128][40];
    __shared__ ushort_t Bs[128][40];
    int tid = threadIdx.x;
    int m0 = blockIdx.x * 128;
    int n0 = blockIdx.y * 128;
    int lane = tid & 63, w = tid >> 6;
    int wr = w >> 1, wc = w & 1;
    int quad = lane >> 4, lm = lane & 15;
    f32x4 acc[4][4] = {};
    for (int k0 = 0; k0 < 256; k0 += 32) {
        #pragma unroll
        for (int i = 0; i < 2; ++i) {
            int c = i * 256 + tid;
            int r = c >> 2, kq = c & 3;
            *(uint4*)&As[r][kq * 8] = *(const uint4*)&Abf[(m0 + r) * 256 + k0 + kq * 8];
            *(uint4*)&Bs[r][kq * 8] = *(const uint4*)&Wt[(n0 + r) * 256 + k0 + kq * 8];
        }
        __syncthreads();
        s16x8 af[4], bf_[4];
        #pragma unroll
        for (int mi = 0; mi < 4; ++mi)
            af[mi] = *(const s16x8*)&As[wr * 64 + mi * 16 + lm][quad * 8];
        #pragma unroll
        for (int ni = 0; ni < 4; ++ni)
            bf_[ni] = *(const s16x8*)&Bs[wc * 64 + ni * 16 + lm][quad * 8];
        #pragma unroll
        for (int mi = 0; mi < 4; ++mi)
            #pragma unroll
            for (int ni = 0; ni < 4; ++ni)
                acc[mi][ni] = __builtin_amdgcn_mfma_f32_16x16x32_bf16(
                    af[mi], bf_[ni], acc[mi][ni], 0, 0, 0);
        __syncthreads();
    }
    bool isz = (n0 >= 512);
    ushort_t* out = isz ? zb : xinb;
    int nb = isz ? n0 - 512 : n0;
    #pragma unroll
    for (int mi = 0; mi < 4; ++mi) {
        #pragma unroll
        for (int ni = 0; ni < 4; ++ni) {
            int colg = nb + wc * 64 + ni * 16 + lm;
            #pragma unroll
            for (int r = 0; r < 4; ++r) {
                int rowg = m0 + wr * 64 + mi * 16 + quad * 4 + r;
                out[rowg * 512 + colg] = f2bf(acc[mi][ni][r]);
            }
        }
    }
}

// ---------------- depthwise causal conv(4) + SiLU -> bf16 xcb --------------
__global__ __launch_bounds__(256) void k_conv(const ushort_t* __restrict__ xinb,
                                              const float* __restrict__ cw,
                                              const float* __restrict__ cb,
                                              ushort_t* __restrict__ xcb) {
    int idx = blockIdx.x * 256 + threadIdx.x;
    int d = idx & 511;
    int r = idx >> 9;
    int l = r & 4095;
    int b = r >> 12;
    float s = cb[d];
    #pragma unroll
    for (int k = 0; k < 4; ++k) {
        int ll = l - 3 + k;
        if (ll >= 0) s += cw[d * 4 + k] * bf2f(xinb[(((b << 12) + ll) << 9) + d]);
    }
    float sig = 1.f / (1.f + expf(-s));
    xcb[idx] = f2bf(s * sig);
}

// ---------------- x-proj (MFMA): dbl = xc @ W_x -> dtr/Bm/Cm ---------------
__global__ __launch_bounds__(256) void k_xproj1(const ushort_t* __restrict__ xcb,
                                                const ushort_t* __restrict__ Wxt,
                                                float* __restrict__ dtr,
                                                float* __restrict__ Bm,
                                                float* __restrict__ Cm) {
    __shared__ ushort_t As[64][72];
    __shared__ ushort_t Bs[48][72];
    int tid = threadIdx.x;
    int m0 = blockIdx.x * 64;
    int lane = tid & 63, w = tid >> 6;
    int quad = lane >> 4, lm = lane & 15;
    f32x4 acc[3] = {};
    for (int k0 = 0; k0 < 512; k0 += 64) {
        #pragma unroll
        for (int i = 0; i < 2; ++i) {
            int f = i * 256 + tid;
            int r = f >> 3, kq = f & 7;
            *(uint4*)&As[r][kq * 8] = *(const uint4*)&xcb[(m0 + r) * 512 + k0 + kq * 8];
        }
        if (tid < 192) {
            #pragma unroll
            for (int i = 0; i < 2; ++i) {
                int f = i * 192 + tid;
                int r = f >> 3, kq = f & 7;
                *(uint4*)&Bs[r][kq * 8] = *(const uint4*)&Wxt[r * 512 + k0 + kq * 8];
            }
        }
        __syncthreads();
        #pragma unroll
        for (int kk = 0; kk < 2; ++kk) {
            s16x8 af = *(const s16x8*)&As[w * 16 + lm][kk * 32 + quad * 8];
            #pragma unroll
            for (int nt = 0; nt < 3; ++nt) {
                s16x8 bv = *(const s16x8*)&Bs[nt * 16 + lm][kk * 32 + quad * 8];
                acc[nt] = __builtin_amdgcn_mfma_f32_16x16x32_bf16(af, bv, acc[nt], 0, 0, 0);
            }
        }
        __syncthreads();
    }
    #pragma unroll
    for (int nt = 0; nt < 3; ++nt) {
        float* dst = (nt == 0) ? dtr : ((nt == 1) ? Bm : Cm);
        #pragma unroll
        for (int r = 0; r < 4; ++r) {
            int row = m0 + w * 16 + quad * 4 + r;
            dst[row * 16 + lm] = acc[nt][r];
        }
    }
}

// ---------------- dt-proj: dtp = softplus(dtr @ W_dt + b_dt) ----------------
__global__ __launch_bounds__(256) void k_dtproj(const float* __restrict__ dtr,
                                                const float* __restrict__ Wdt,
                                                const float* __restrict__ bdt,
                                                float* __restrict__ dtp) {
    int tid = threadIdx.x;
    int t0 = blockIdx.x * 16;
    __shared__ float R[16][17];
    float w0[16], w1[16];
    #pragma unroll
    for (int r = 0; r < 16; ++r) {
        w0[r] = Wdt[r * 512 + tid];
        w1[r] = Wdt[r * 512 + 256 + tid];
    }
    float b0 = bdt[tid], b1 = bdt[256 + tid];
    {
        int t = tid >> 4, r = tid & 15;
        R[t][r] = dtr[(t0 + t) * 16 + r];
    }
    __syncthreads();
    for (int t = 0; t < 16; ++t) {
        float s0 = b0, s1 = b1;
        #pragma unroll
        for (int r = 0; r < 16; ++r) {
            float dv = R[t][r];
            s0 += dv * w0[r];
            s1 += dv * w1[r];
        }
        s0 = (s0 > 20.f) ? s0 : log1pf(expf(s0));
        s1 = (s1 > 20.f) ? s1 : log1pf(expf(s1));
        dtp[(t0 + t) * 512 + tid] = s0;
        dtp[(t0 + t) * 512 + 256 + tid] = s1;
    }
}

// ---------------- scan phase A: S layout [b][c][n][d] ----------------
__global__ __launch_bounds__(512) void k_scanA(const float* __restrict__ dtp,
                                               const ushort_t* __restrict__ xcb,
                                               const float* __restrict__ Bm,
                                               const float* __restrict__ A_log,
                                               float* __restrict__ S,
                                               float* __restrict__ sdt) {
    int b = blockIdx.x >> 7;
    int ch = blockIdx.x & 127;
    int d = threadIdx.x;
    __shared__ float Bb[CT][16];
    {
        int t = threadIdx.x >> 4, n = threadIdx.x & 15;
        Bb[t][n] = Bm[((b << 12) + ch * CT + t) * 16 + n];
    }
    __syncthreads();
    float a2[16];
    #pragma unroll
    for (int n = 0; n < 16; ++n) a2[n] = -expf(A_log[d * 16 + n]) * LOG2E;
    float h[16] = {};
    float sum_dt = 0.f;
    int base = ((b << 12) + ch * CT) * 512 + d;
    for (int t = 0; t < CT; ++t) {
        float dv = dtp[base + t * 512];
        float xv = bf2f(xcb[base + t * 512]);
        sum_dt += dv;
        float dx = dv * xv;
        #pragma unroll
        for (int n = 0; n < 16; ++n) {
            float w = exp2f(dv * a2[n]);
            h[n] = w * h[n] + dx * Bb[t][n];
        }
    }
    int so = ((b * NC + ch) * 16) * 512 + d;
    #pragma unroll
    for (int n = 0; n < 16; ++n)
        S[so + n * 512] = h[n];
    sdt[(b * NC + ch) * 512 + d] = sum_dt;
}

// ---------------- comb phase A: per-segment compose (16 chunks) ------------
// grid: 256 blocks = (b,n,seg); 512 thr = d. Wsg/Ssg: [b][n][seg][d]
__global__ __launch_bounds__(512) void k_combA(const float* __restrict__ S,
                                               const float* __restrict__ sdt,
                                               const float* __restrict__ A_log,
                                               float* __restrict__ Wsg,
                                               float* __restrict__ Ssg) {
    int bi = blockIdx.x;
    int b = bi >> 7, n = (bi >> 3) & 15, seg = bi & 7;
    int d = threadIdx.x;
    float a2 = -expf(A_log[d * 16 + n]) * LOG2E;
    float Wc = 1.f, Sc = 0.f;
    #pragma unroll
    for (int i = 0; i < 16; ++i) {
        int c = seg * 16 + i;
        float w = exp2f(a2 * sdt[(b * NC + c) * 512 + d]);
        float s = S[((b * NC + c) * 16 + n) * 512 + d];
        Sc = w * Sc + s;
        Wc *= w;
    }
    int o = ((b * 16 + n) * 8 + seg) * 512 + d;
    Wsg[o] = Wc;
    Ssg[o] = Sc;
}

// ---------------- comb phase B: prefix over 8 segments ----------------
// grid: 32 blocks = (b,n); 512 thr = d. hpre: [b][n][seg][d]
__global__ __launch_bounds__(512) void k_combB(const float* __restrict__ Wsg,
                                               const float* __restrict__ Ssg,
                                               float* __restrict__ hpre) {
    int bi = blockIdx.x;
    int b = bi >> 4, n = bi & 15;
    int d = threadIdx.x;
    int o0 = ((b * 16 + n) * 8) * 512 + d;
    float h = 0.f;
    #pragma unroll
    for (int seg = 0; seg < 8; ++seg) {
        int o = o0 + seg * 512;
        float W = Wsg[o], Sv = Ssg[o];
        hpre[o] = h;
        h = W * h + Sv;
    }
}

// ---------------- comb phase C: replay within segment, hinit in place ------
__global__ __launch_bounds__(512) void k_combC(float* S,
                                               const float* __restrict__ sdt,
                                               const float* __restrict__ A_log,
                                               const float* __restrict__ hpre) {
    int bi = blockIdx.x;
    int b = bi >> 7, n = (bi >> 3) & 15, seg = bi & 7;
    int d = threadIdx.x;
    float a2 = -expf(A_log[d * 16 + n]) * LOG2E;
    float h = hpre[((b * 16 + n) * 8 + seg) * 512 + d];
    #pragma unroll
    for (int i = 0; i < 16; ++i) {
        int c = seg * 16 + i;
        int si = ((b * NC + c) * 16 + n) * 512 + d;
        float w = exp2f(a2 * sdt[(b * NC + c) * 512 + d]);
        float sval = S[si];
        S[si] = h;
        h = w * h + sval;
    }
}

// ---------------- scan phase C: replay + skip + SiLU gate -> bf16 ----------
__global__ __launch_bounds__(512) void k_scanC(const float* __restrict__ dtp,
                                               const ushort_t* __restrict__ xcb,
                                               const float* __restrict__ Bm,
                                               const float* __restrict__ Cm,
                                               const float* __restrict__ A_log,
                                               const float* __restrict__ hinit,
                                               const float* __restrict__ Dskip,
                                               const ushort_t* __restrict__ zb,
                                               ushort_t* __restrict__ yact) {
    int b = blockIdx.x >> 7;
    int ch = blockIdx.x & 127;
    int d = threadIdx.x;
    __shared__ float Bb[CT][16], Cb[CT][16];
    {
        int t = threadIdx.x >> 4, n = threadIdx.x & 15;
        int li = ((b << 12) + ch * CT + t) * 16 + n;
        Bb[t][n] = Bm[li];
        Cb[t][n] = Cm[li];
    }
    __syncthreads();
    float a2[16], h[16];
    #pragma unroll
    for (int n = 0; n < 16; ++n) a2[n] = -expf(A_log[d * 16 + n]) * LOG2E;
    int hi = ((b * NC + ch) * 16) * 512 + d;
    #pragma unroll
    for (int n = 0; n < 16; ++n) h[n] = hinit[hi + n * 512];
    float Dsk = Dskip[d];
    int base = ((b << 12) + ch * CT) * 512 + d;
    for (int t = 0; t < CT; ++t) {
        float dv = dtp[base + t * 512];
        float xv = bf2f(xcb[base + t * 512]);
        float zv = bf2f(zb[base + t * 512]);
        float dx = dv * xv;
        float y = 0.f;
        #pragma unroll
        for (int n = 0; n < 16; ++n) {
            float w = exp2f(dv * a2[n]);
            h[n] = w * h[n] + dx * Bb[t][n];
            y += h[n] * Cb[t][n];
        }
        y += xv * Dsk;
        float sig = 1.f / (1.f + expf(-zv));
        yact[base + t * 512] = f2bf(y * zv * sig);
    }
}

// ---------------- GEMM3 (MFMA bf16): out = yact @ W_out, transposed store --
__global__ __launch_bounds__(256) void k_gemm3(const ushort_t* __restrict__ Abf,
                                               const ushort_t* __restrict__ Wt3,
                                               float* __restrict__ out) {
    __shared__ ushort_t As[128][40];
    __shared__ ushort_t Bs[64][40];
    __shared__ float T[64][132];
    int tid = threadIdx.x;
    int m0 = blockIdx.x * 128;
    int n0 = blockIdx.y * 64;
    int lane = tid & 63, w = tid >> 6;
    int wr = w >> 1, wc = w & 1;
    int quad = lane >> 4, lm = lane & 15;
    f32x4 acc[4][2] = {};
    for (int k0 = 0; k0 < 512; k0 += 32) {
        #pragma unroll
        for (int i = 0; i < 2; ++i) {
            int c = i * 256 + tid;
            int r = c >> 2, kq = c & 3;
            *(uint4*)&As[r][kq * 8] = *(const uint4*)&Abf[(m0 + r) * 512 + k0 + kq * 8];
        }
        {
            int r = tid >> 2, kq = tid & 3;
            *(uint4*)&Bs[r][kq * 8] = *(const uint4*)&Wt3[(n0 + r) * 512 + k0 + kq * 8];
        }
        __syncthreads();
        s16x8 af[4], bf_[2];
        #pragma unroll
        for (int mi = 0; mi < 4; ++mi)
            af[mi] = *(const s16x8*)&As[wr * 64 + mi * 16 + lm][quad * 8];
        #pragma unroll
        for (int ni = 0; ni < 2; ++ni)
            bf_[ni] = *(const s16x8*)&Bs[wc * 32 + ni * 16 + lm][quad * 8];
        #pragma unroll
        for (int mi = 0; mi < 4; ++mi)
            #pragma unroll
            for (int ni = 0; ni < 2; ++ni)
                acc[mi][ni] = __builtin_amdgcn_mfma_f32_16x16x32_bf16(
                    af[mi], bf_[ni], acc[mi][ni], 0, 0, 0);
        __syncthreads();
    }
    #pragma unroll
    for (int mi = 0; mi < 4; ++mi)
        #pragma unroll
        for (int ni = 0; ni < 2; ++ni)
            #pragma unroll
            for (int r = 0; r < 4; ++r)
                T[wc * 32 + ni * 16 + lm][wr * 64 + mi * 16 + quad * 4 + r] = acc[mi][ni][r];
    __syncthreads();
    int b = m0 >> 12;
    int l0 = m0 & 4095;
    #pragma unroll
    for (int i = 0; i < 8; ++i) {
        int f = i * 256 + tid;
        int col = f >> 5, lq = f & 31;
        float4 v = *(float4*)&T[col][lq * 4];
        *(float4*)(out + b * (256 * 4096) + (n0 + col) * 4096 + l0 + lq * 4) = v;
    }
}

extern "C" void kernel_launch(void* const* d_in, const int* in_sizes, int n_in,
                              void* d_out, int out_size, void* d_ws, size_t ws_size,
                              hipStream_t stream) {
    const float* x      = (const float*)d_in[0];
    const float* ln_g   = (const float*)d_in[1];
    const float* ln_b   = (const float*)d_in[2];
    const float* W_in   = (const float*)d_in[3];
    const float* conv_w = (const float*)d_in[4];
    const float* conv_b = (const float*)d_in[5];
    const float* W_x    = (const float*)d_in[6];
    const float* W_dt   = (const float*)d_in[7];
    const float* b_dt   = (const float*)d_in[8];
    const float* A_log  = (const float*)d_in[9];
    const float* D_skip = (const float*)d_in[10];
    const float* W_out  = (const float*)d_in[11];
    float* out = (float*)d_out;

    float* ws = (float*)d_ws;
    float* dtp  = ws;                      // 4,194,304 f
    float* Bm   = dtp + 4194304;           // 131,072 f
    float* Cm   = Bm + 131072;             // 131,072 f
    float* Sst  = Cm + 131072;             // 2,097,152 f  (hinit in place)
    float* sdt  = Sst + 2097152;           // 131,072 f
    float* dtr  = sdt + 131072;            // 131,072 f
    float* Wsg  = dtr + 131072;            // 131,072 f
    float* Ssg  = Wsg + 131072;            // 131,072 f
    float* hpre = Ssg + 131072;            // 131,072 f
    ushort_t* xs_bf = (ushort_t*)(hpre + 131072);  // 2,097,152 us
    ushort_t* Wt1  = xs_bf + 2097152;      // 262,144 us
    ushort_t* Wt3  = Wt1 + 262144;         // 131,072 us
    ushort_t* Wxt  = Wt3 + 131072;         // 24,576 us (padded to 32,768)
    ushort_t* xinb = Wxt + 32768;          // 4,194,304 us
    ushort_t* zb   = xinb + 4194304;       // 4,194,304 us
    ushort_t* xcb  = zb + 4194304;         // 4,194,304 us
    ushort_t* yact = xinb;                 // alias: xinb dead after conv

    k_prep  <<<dim3(480),   dim3(256), 0, stream>>>(W_in, W_out, W_x, Wt1, Wt3, Wxt);
    k_ln    <<<dim3(256),   dim3(256), 0, stream>>>(x, ln_g, ln_b, xs_bf);
    k_gemm1 <<<dim3(64, 8), dim3(256), 0, stream>>>(xs_bf, Wt1, xinb, zb);
    k_conv  <<<dim3(16384), dim3(256), 0, stream>>>(xinb, conv_w, conv_b, xcb);
    k_xproj1<<<dim3(128),   dim3(256), 0, stream>>>(xcb, Wxt, dtr, Bm, Cm);
    k_dtproj<<<dim3(512),   dim3(256), 0, stream>>>(dtr, W_dt, b_dt, dtp);
    k_scanA <<<dim3(256),   dim3(512), 0, stream>>>(dtp, xcb, Bm, A_log, Sst, sdt);
    k_combA <<<dim3(256),   dim3(512), 0, stream>>>(Sst, sdt, A_log, Wsg, Ssg);
    k_combB <<<dim3(32),    dim3(512), 0, stream>>>(Wsg, Ssg, hpre);
    k_combC <<<dim3(256),   dim3(512), 0, stream>>>(Sst, sdt, A_log, hpre);
    k_scanC <<<dim3(256),   dim3(512), 0, stream>>>(dtp, xcb, Bm, Cm, A_log, Sst,
                                                    D_skip, zb, yact);
    k_gemm3 <<<dim3(64, 4), dim3(256), 0, stream>>>(yact, Wt3, out);
}